// Round 3
// baseline (96.349 us; speedup 1.0000x reference)
//
#include <hip/hip_runtime.h>

#define B_ 16
#define C_ 64
#define N_ 16384          // 128*128
#define SROW 72           // Xt row stride in bf16 (pad 64 -> 72, keeps 8B alignment for b64/b128)

typedef __attribute__((ext_vector_type(8))) short bf16x8;
typedef __attribute__((ext_vector_type(4))) float f32x4;
typedef __attribute__((ext_vector_type(4))) short s16x4;

// fp32 -> bf16 round-to-nearest-even, bit form
__device__ __forceinline__ short f2bf(float f) {
    unsigned int u = __float_as_uint(f);
    unsigned int r = (u + 0x7FFFu + ((u >> 16) & 1u)) >> 16;
    return (short)r;
}

// -------- pass 1: per-(batch, k-chunk) partial gram via bf16 MFMA --------
// 4 waves/block, NO LDS, NO barriers: wave w owns gram tile-row gc=w
// (tiles (w, 0..3)) and sweeps the block's whole column range. A-fragment
// loaded directly from rows 16w+row (redundant with frag[w] but L1-hot;
// avoids runtime-indexed register array -> scratch). Partials written
// per-tile, disjoint per wave -> no reduction needed.
__global__ __launch_bounds__(256, 4)
void gram_kernel(const float* __restrict__ x, float* __restrict__ gpart, int nks) {
    const int t = threadIdx.x, l = t & 63, w = t >> 6;
    const int b = blockIdx.y, ch = blockIdx.x;
    const float* xb = x + (size_t)b * (C_ * (size_t)N_);
    const int row = l & 15, kg = l >> 4;
    const int kbase = ch * nks * 32;

    f32x4 acc[4] = {};

    for (int ks = 0; ks < nks; ++ks) {
        const int k0 = kbase + ks * 32 + kg * 8;
        bf16x8 frag[4], fa;
        #pragma unroll
        for (int g = 0; g < 4; ++g) {
            const float* p = xb + (size_t)(16 * g + row) * N_ + k0;
            float4 lo = *(const float4*)p;
            float4 hi = *(const float4*)(p + 4);
            bf16x8 f;
            f[0] = f2bf(lo.x); f[1] = f2bf(lo.y); f[2] = f2bf(lo.z); f[3] = f2bf(lo.w);
            f[4] = f2bf(hi.x); f[5] = f2bf(hi.y); f[6] = f2bf(hi.z); f[7] = f2bf(hi.w);
            frag[g] = f;
        }
        {   // A-fragment: rows 16w + row (compile-time-free index, L1-hot reload)
            const float* p = xb + (size_t)(16 * w + row) * N_ + k0;
            float4 lo = *(const float4*)p;
            float4 hi = *(const float4*)(p + 4);
            bf16x8 f;
            f[0] = f2bf(lo.x); f[1] = f2bf(lo.y); f[2] = f2bf(lo.z); f[3] = f2bf(lo.w);
            f[4] = f2bf(hi.x); f[5] = f2bf(hi.y); f[6] = f2bf(hi.z); f[7] = f2bf(hi.w);
            fa = f;
        }
        #pragma unroll
        for (int gd = 0; gd < 4; ++gd)
            acc[gd] = __builtin_amdgcn_mfma_f32_16x16x32_bf16(fa, frag[gd], acc[gd], 0, 0, 0);
    }

    // tile = w*4 + gd, flat layout [tile*256 + lane*4 + reg]
    float* dst = gpart + ((size_t)b * gridDim.x + ch) * 4096 + (size_t)w * 1024;
    #pragma unroll
    for (int gd = 0; gd < 4; ++gd)
        *(f32x4*)(dst + gd * 256 + l * 4) = acc[gd];
}

// -------- pass 2: reduce partials, decode C-layout, apply W, emit bf16 M --------
// grid (4, B): block (gd, b) reduces its 4 tiles (gc=0..3) over all chunks,
// computes M[o][d] = (1/N) sum_c W[o][c] G[c][d] for d in gd's 16-col slice.
__global__ __launch_bounds__(256)
void m_kernel(const float* __restrict__ W, const float* __restrict__ gpart,
              unsigned short* __restrict__ Mbf, int kch) {
    __shared__ float Gs[C_][17];   // [c][dloc]
    __shared__ float Ws[C_][65];   // [o][c]
    const int gd = blockIdx.x, b = blockIdx.y, t = threadIdx.x;

    for (int i = t; i < C_ * C_; i += 256) Ws[i >> 6][i & 63] = W[i];

    const int f = t;  // flat in-tile index = lane*4 + reg
    #pragma unroll
    for (int gc = 0; gc < 4; ++gc) {
        const float* p = gpart + (size_t)b * kch * 4096 + (gc * 4 + gd) * 256 + f;
        float s0 = 0.f, s1 = 0.f, s2 = 0.f, s3 = 0.f;
        for (int ch = 0; ch < kch; ch += 4) {
            s0 += p[(size_t)(ch + 0) * 4096];
            s1 += p[(size_t)(ch + 1) * 4096];
            s2 += p[(size_t)(ch + 2) * 4096];
            s3 += p[(size_t)(ch + 3) * 4096];
        }
        // decode: c = gc*16 + (lane>>4)*4 + reg, dloc = lane&15
        const int c = gc * 16 + (f >> 6) * 4 + (f & 3);
        const int dloc = (f >> 2) & 15;
        Gs[c][dloc] = (s0 + s1) + (s2 + s3);
    }
    __syncthreads();

    const int o = t & 63, g2 = t >> 6;
    const float invN = 1.0f / (float)N_;
    #pragma unroll
    for (int j = 0; j < 4; ++j) {
        const int dloc = g2 * 4 + j;
        float s = 0.f;
        #pragma unroll
        for (int c = 0; c < C_; ++c) s = fmaf(Ws[o][c], Gs[c][dloc], s);
        Mbf[((size_t)b * C_ + o) * C_ + gd * 16 + dloc] = (unsigned short)f2bf(s * invN);
    }
}

// -------- pass 3: out_b = M_b @ X_b via bf16 MFMA --------
// A = M row-major bf16 (fragments straight from global, L3-hot).
// B = X staged transposed in LDS: pack-4 ds_write_b64 (d-quad per write),
// 16 writes/thread, lanes 0-15 cover all 32 banks.
__global__ __launch_bounds__(256, 4)
void out_kernel(const float* __restrict__ x, const unsigned short* __restrict__ Mbf,
                float* __restrict__ out) {
    __shared__ unsigned short Xt[256][SROW];   // 36 KiB
    const int t = threadIdx.x, l = t & 63, w = t >> 6;
    const int b = blockIdx.y, n0 = blockIdx.x * 256;
    const float* xb = x + (size_t)b * (C_ * (size_t)N_);
    const int row = l & 15, kg = l >> 4;

    // A fragments: lane l -> M[16g+row][ks*32 + kg*8 + j]
    bf16x8 afrag[2][4];
    #pragma unroll
    for (int ks = 0; ks < 2; ++ks)
        #pragma unroll
        for (int g = 0; g < 4; ++g)
            afrag[ks][g] = *(const bf16x8*)((const short*)Mbf +
                ((size_t)b * C_ + 16 * g + row) * C_ + ks * 32 + kg * 8);

    // stage+transpose: thread t -> d-quad d0 = (t&15)*4, n-block = (t>>4)*16,
    // processed in two 8-n halves to bound register pressure.
    const int d0 = (t & 15) * 4, nb = (t >> 4) * 16;
    #pragma unroll
    for (int p = 0; p < 2; ++p) {
        const int n8 = nb + p * 8;
        float a[4][8];
        #pragma unroll
        for (int r = 0; r < 4; ++r) {
            const float* src = xb + (size_t)(d0 + r) * N_ + n0 + n8;
            float4 q0 = *(const float4*)src;
            float4 q1 = *(const float4*)(src + 4);
            a[r][0] = q0.x; a[r][1] = q0.y; a[r][2] = q0.z; a[r][3] = q0.w;
            a[r][4] = q1.x; a[r][5] = q1.y; a[r][6] = q1.z; a[r][7] = q1.w;
        }
        #pragma unroll
        for (int j = 0; j < 8; ++j) {
            s16x4 pk;
            pk[0] = f2bf(a[0][j]); pk[1] = f2bf(a[1][j]);
            pk[2] = f2bf(a[2][j]); pk[3] = f2bf(a[3][j]);
            *(s16x4*)&Xt[n8 + j][d0] = pk;   // ds_write_b64
        }
    }
    __syncthreads();

    float* ob = out + (size_t)b * (C_ * (size_t)N_);
    #pragma unroll
    for (int nt = 0; nt < 4; ++nt) {
        const int ntile = w * 4 + nt;
        bf16x8 bfrag0 = *(const bf16x8*)&Xt[ntile * 16 + row][kg * 8];
        bf16x8 bfrag1 = *(const bf16x8*)&Xt[ntile * 16 + row][32 + kg * 8];
        #pragma unroll
        for (int g = 0; g < 4; ++g) {
            f32x4 acc = {};
            acc = __builtin_amdgcn_mfma_f32_16x16x32_bf16(afrag[0][g], bfrag0, acc, 0, 0, 0);
            acc = __builtin_amdgcn_mfma_f32_16x16x32_bf16(afrag[1][g], bfrag1, acc, 0, 0, 0);
            // D: row(o) = 16g + 4kg + r, col(n) = n0 + ntile*16 + row
            #pragma unroll
            for (int r = 0; r < 4; ++r)
                ob[(size_t)(16 * g + 4 * kg + r) * N_ + n0 + ntile * 16 + row] = acc[r];
        }
    }
}

extern "C" void kernel_launch(void* const* d_in, const int* in_sizes, int n_in,
                              void* d_out, int out_size, void* d_ws, size_t ws_size,
                              hipStream_t stream) {
    const float* x = (const float*)d_in[0];   // [16,64,128,128] fp32
    const float* w = (const float*)d_in[1];   // [64,64] fp32
    float* out = (float*)d_out;               // [16,64,128,128] fp32

    // kch=64 needs 16 MiB partials + 128 KiB M; fall back to 32 if ws is small
    const size_t need64 = (size_t)B_ * 64 * 4096 * 4 + (size_t)B_ * C_ * C_ * 2;
    const int kch = (ws_size >= need64) ? 64 : 32;
    const int nks = (N_ / kch) / 32;

    float* gpart = (float*)d_ws;
    unsigned short* Mbf = (unsigned short*)((char*)d_ws + (size_t)B_ * kch * 4096 * 4);

    gram_kernel<<<dim3(kch, B_), 256, 0, stream>>>(x, gpart, nks);
    m_kernel<<<dim3(4, B_), 256, 0, stream>>>(w, gpart, Mbf, kch);
    out_kernel<<<dim3(N_ / 256, B_), 256, 0, stream>>>(x, Mbf, out);
}

// Round 4
// 55.280 us; speedup vs baseline: 1.7429x; 1.7429x over previous
//
#include <hip/hip_runtime.h>

#define B_ 16
#define C_ 64
#define N_ 16384          // 128*128
#define KCH 32            // gram chunks per batch -> 512 blocks
#define CPB 512           // columns per gram block (N_/KCH)
#define SROW 72           // Xt row stride in bf16 (pad 64 -> 72)

typedef __attribute__((ext_vector_type(8))) short bf16x8;
typedef __attribute__((ext_vector_type(4))) float f32x4;
typedef __attribute__((ext_vector_type(4))) short s16x4;

// fp32 -> bf16 round-to-nearest-even, bit form
__device__ __forceinline__ short f2bf(float f) {
    unsigned int u = __float_as_uint(f);
    unsigned int r = (u + 0x7FFFu + ((u >> 16) & 1u)) >> 16;
    return (short)r;
}

__device__ __forceinline__ bf16x8 cvt8(float4 lo, float4 hi) {
    bf16x8 r;
    r[0] = f2bf(lo.x); r[1] = f2bf(lo.y); r[2] = f2bf(lo.z); r[3] = f2bf(lo.w);
    r[4] = f2bf(hi.x); r[5] = f2bf(hi.y); r[6] = f2bf(hi.z); r[7] = f2bf(hi.w);
    return r;
}

// -------- pass 1: per-(batch, k-chunk) partial gram via bf16 MFMA --------
// 4 waves/block, wave w owns columns [ch*512 + w*128, +128): 4 k-steps of 32.
// Each wave computes the FULL 64x64 gram partial (16 tiles, 64 acc VGPRs).
// Explicit double-buffered raw float4 arrays (compile-time indexed after
// unroll) force ~64 load-destination VGPRs live -> the 8 dwordx4 loads of a
// k-step stay batched in flight under the cvt+MFMA of the previous step
// (round-3 lesson: a small register footprint lets the compiler serialize
// HBM loads -> 44us at 14% BW).
__global__ __launch_bounds__(256)
void gram_kernel(const float* __restrict__ x, float* __restrict__ gpart) {
    __shared__ float red[2][4096];   // 32 KiB two-phase reduce buffer
    const int t = threadIdx.x, l = t & 63, w = t >> 6;
    const int b = blockIdx.y, ch = blockIdx.x;
    const float* xb = x + (size_t)b * (C_ * (size_t)N_);
    const int row = l & 15, kg = l >> 4;
    const int kbase = ch * CPB + w * (CPB / 4);

    f32x4 acc[4][4] = {};
    float4 raw[2][4][2];

    // preload k-step 0
    #pragma unroll
    for (int g = 0; g < 4; ++g) {
        const float* p = xb + (size_t)(16 * g + row) * N_ + kbase + kg * 8;
        raw[0][g][0] = *(const float4*)p;
        raw[0][g][1] = *(const float4*)(p + 4);
    }

    #pragma unroll
    for (int ks = 0; ks < 4; ++ks) {
        const int cb = ks & 1, nb = cb ^ 1;
        if (ks < 3) {   // issue next k-step's 8 loads before touching current
            #pragma unroll
            for (int g = 0; g < 4; ++g) {
                const float* p = xb + (size_t)(16 * g + row) * N_ +
                                 kbase + (ks + 1) * 32 + kg * 8;
                raw[nb][g][0] = *(const float4*)p;
                raw[nb][g][1] = *(const float4*)(p + 4);
            }
        }
        bf16x8 fr[4];
        #pragma unroll
        for (int g = 0; g < 4; ++g) fr[g] = cvt8(raw[cb][g][0], raw[cb][g][1]);
        #pragma unroll
        for (int gc = 0; gc < 4; ++gc)
            #pragma unroll
            for (int gd = 0; gd < 4; ++gd)
                acc[gc][gd] = __builtin_amdgcn_mfma_f32_16x16x32_bf16(
                    fr[gc], fr[gd], acc[gc][gd], 0, 0, 0);
    }

    // two-phase block reduce: waves 0,1 write; waves 2,3 add; all sum halves.
    if (w < 2) {
        #pragma unroll
        for (int gc = 0; gc < 4; ++gc)
            #pragma unroll
            for (int gd = 0; gd < 4; ++gd)
                *(f32x4*)&red[w][(gc * 4 + gd) * 256 + l * 4] = acc[gc][gd];
    }
    __syncthreads();
    if (w >= 2) {
        #pragma unroll
        for (int gc = 0; gc < 4; ++gc)
            #pragma unroll
            for (int gd = 0; gd < 4; ++gd) {
                float* p = &red[w - 2][(gc * 4 + gd) * 256 + l * 4];
                f32x4 v = *(f32x4*)p;
                *(f32x4*)p = v + acc[gc][gd];
            }
    }
    __syncthreads();

    f32x4* dst = (f32x4*)(gpart + ((size_t)b * KCH + ch) * 4096);
    const f32x4* r0 = (const f32x4*)red[0];
    const f32x4* r1 = (const f32x4*)red[1];
    #pragma unroll
    for (int j = 0; j < 4; ++j)
        dst[j * 256 + t] = r0[j * 256 + t] + r1[j * 256 + t];
}

// -------- pass 2a: reduce chunk partials, fully coalesced --------
// 256 blocks x 256 threads = 65536 threads, one per G element (MFMA-flat
// layout preserved). Consecutive threads read consecutive addresses.
__global__ __launch_bounds__(256)
void reduce_kernel(const float* __restrict__ gpart, float* __restrict__ G) {
    const int gid = blockIdx.x * 256 + threadIdx.x;   // 0..65535
    const int b = gid >> 12, e = gid & 4095;
    const float* p = gpart + ((size_t)b * KCH) * 4096 + e;
    float s0 = 0.f, s1 = 0.f, s2 = 0.f, s3 = 0.f;
    #pragma unroll
    for (int ch = 0; ch < KCH; ch += 4) {
        s0 += p[(size_t)(ch + 0) * 4096];
        s1 += p[(size_t)(ch + 1) * 4096];
        s2 += p[(size_t)(ch + 2) * 4096];
        s3 += p[(size_t)(ch + 3) * 4096];
    }
    G[gid] = (s0 + s1) + (s2 + s3);
}

// -------- pass 2b (tiny): decode C-layout, apply W, emit bf16 M --------
// block (gd, b): M[o][gd*16+dloc] = (1/N) sum_c W[o][c] G_b[c][gd*16+dloc]
__global__ __launch_bounds__(256)
void m_kernel(const float* __restrict__ W, const float* __restrict__ G,
              unsigned short* __restrict__ Mbf) {
    __shared__ float Gs[C_][17];   // [c][dloc]
    __shared__ float Ws[C_][65];   // [o][c]
    const int gd = blockIdx.x, b = blockIdx.y, t = threadIdx.x;

    for (int i = t; i < C_ * C_; i += 256) Ws[i >> 6][i & 63] = W[i];

    const int f = t;  // flat in-tile index = lane*4 + reg
    #pragma unroll
    for (int gc = 0; gc < 4; ++gc) {
        float s = G[(size_t)b * 4096 + (gc * 4 + gd) * 256 + f];
        // decode: c = gc*16 + (lane>>4)*4 + reg, dloc = lane&15
        const int c = gc * 16 + (f >> 6) * 4 + (f & 3);
        const int dloc = (f >> 2) & 15;
        Gs[c][dloc] = s;
    }
    __syncthreads();

    const int o = t & 63, g2 = t >> 6;
    const float invN = 1.0f / (float)N_;
    #pragma unroll
    for (int j = 0; j < 4; ++j) {
        const int dloc = g2 * 4 + j;
        float s = 0.f;
        #pragma unroll
        for (int c = 0; c < C_; ++c) s = fmaf(Ws[o][c], Gs[c][dloc], s);
        Mbf[((size_t)b * C_ + o) * C_ + gd * 16 + dloc] = (unsigned short)f2bf(s * invN);
    }
}

// -------- pass 3: out_b = M_b @ X_b via bf16 MFMA --------
// A = M row-major bf16 (fragments straight from global, L3-hot).
// B = X staged transposed in LDS: pack-4 ds_write_b64 (d-quad per write).
__global__ __launch_bounds__(256, 4)
void out_kernel(const float* __restrict__ x, const unsigned short* __restrict__ Mbf,
                float* __restrict__ out) {
    __shared__ unsigned short Xt[256][SROW];   // 36 KiB
    const int t = threadIdx.x, l = t & 63, w = t >> 6;
    const int b = blockIdx.y, n0 = blockIdx.x * 256;
    const float* xb = x + (size_t)b * (C_ * (size_t)N_);
    const int row = l & 15, kg = l >> 4;

    // A fragments: lane l -> M[16g+row][ks*32 + kg*8 + j]
    bf16x8 afrag[2][4];
    #pragma unroll
    for (int ks = 0; ks < 2; ++ks)
        #pragma unroll
        for (int g = 0; g < 4; ++g)
            afrag[ks][g] = *(const bf16x8*)((const short*)Mbf +
                ((size_t)b * C_ + 16 * g + row) * C_ + ks * 32 + kg * 8);

    // stage+transpose: thread t -> d-quad d0 = (t&15)*4, n-block = (t>>4)*16,
    // two 8-n halves to bound register pressure; ds_write_b64 packs 4 d's.
    const int d0 = (t & 15) * 4, nb2 = (t >> 4) * 16;
    #pragma unroll
    for (int p = 0; p < 2; ++p) {
        const int n8 = nb2 + p * 8;
        float a[4][8];
        #pragma unroll
        for (int r = 0; r < 4; ++r) {
            const float* src = xb + (size_t)(d0 + r) * N_ + n0 + n8;
            float4 q0 = *(const float4*)src;
            float4 q1 = *(const float4*)(src + 4);
            a[r][0] = q0.x; a[r][1] = q0.y; a[r][2] = q0.z; a[r][3] = q0.w;
            a[r][4] = q1.x; a[r][5] = q1.y; a[r][6] = q1.z; a[r][7] = q1.w;
        }
        #pragma unroll
        for (int j = 0; j < 8; ++j) {
            s16x4 pk;
            pk[0] = f2bf(a[0][j]); pk[1] = f2bf(a[1][j]);
            pk[2] = f2bf(a[2][j]); pk[3] = f2bf(a[3][j]);
            *(s16x4*)&Xt[n8 + j][d0] = pk;
        }
    }
    __syncthreads();

    float* ob = out + (size_t)b * (C_ * (size_t)N_);
    #pragma unroll
    for (int nt = 0; nt < 4; ++nt) {
        const int ntile = w * 4 + nt;
        bf16x8 bfrag0 = *(const bf16x8*)&Xt[ntile * 16 + row][kg * 8];
        bf16x8 bfrag1 = *(const bf16x8*)&Xt[ntile * 16 + row][32 + kg * 8];
        #pragma unroll
        for (int g = 0; g < 4; ++g) {
            f32x4 acc = {};
            acc = __builtin_amdgcn_mfma_f32_16x16x32_bf16(afrag[0][g], bfrag0, acc, 0, 0, 0);
            acc = __builtin_amdgcn_mfma_f32_16x16x32_bf16(afrag[1][g], bfrag1, acc, 0, 0, 0);
            #pragma unroll
            for (int r = 0; r < 4; ++r)
                ob[(size_t)(16 * g + 4 * kg + r) * N_ + n0 + ntile * 16 + row] = acc[r];
        }
    }
}

extern "C" void kernel_launch(void* const* d_in, const int* in_sizes, int n_in,
                              void* d_out, int out_size, void* d_ws, size_t ws_size,
                              hipStream_t stream) {
    const float* x = (const float*)d_in[0];   // [16,64,128,128] fp32
    const float* w = (const float*)d_in[1];   // [64,64] fp32
    float* out = (float*)d_out;               // [16,64,128,128] fp32

    float* gpart = (float*)d_ws;                                  // 8 MiB
    float* G = gpart + (size_t)B_ * KCH * 4096;                   // 256 KiB
    unsigned short* Mbf = (unsigned short*)(G + (size_t)B_ * 4096);  // 128 KiB

    gram_kernel<<<dim3(KCH, B_), 256, 0, stream>>>(x, gpart);
    reduce_kernel<<<dim3((B_ * 4096) / 256), 256, 0, stream>>>(gpart, G);
    m_kernel<<<dim3(4, B_), 256, 0, stream>>>(w, G, Mbf);
    out_kernel<<<dim3(N_ / 256, B_), 256, 0, stream>>>(x, Mbf, out);
}